// Round 8
// baseline (328.216 us; speedup 1.0000x reference)
//
#include <hip/hip_runtime.h>
#include <hip/hip_bf16.h>
#include <math.h>

// Problem constants
#define BB 4096
#define DD 2048
#define HH 2048

typedef __bf16 bf16x8 __attribute__((ext_vector_type(8)));
typedef float f32x4 __attribute__((ext_vector_type(4)));

__device__ __forceinline__ void async16(const void* g, void* l) {
  __builtin_amdgcn_global_load_lds(
      (const __attribute__((address_space(1))) unsigned int*)g,
      (__attribute__((address_space(3))) unsigned int*)l,
      16, 0, 0);
}

template <int N>
__device__ __forceinline__ void wait_vmcnt() {
  asm volatile("s_waitcnt vmcnt(%0)" ::"n"(N) : "memory");
}

__device__ __forceinline__ float sigmoidf_(float x) {
  return 1.0f / (1.0f + __expf(-x));
}
__device__ __forceinline__ float tanhf_(float x) {
  float t = __expf(-2.0f * fabsf(x));
  return copysignf((1.0f - t) / (1.0f + t), x);
}

__device__ __forceinline__ void store_bf8(__hip_bfloat16* dst, const float* v) {
  union { __hip_bfloat16 b[8]; uint4 u; } p;
#pragma unroll
  for (int e = 0; e < 8; e++) p.b[e] = __float2bfloat16(v[e]);
  *(uint4*)dst = p.u;
}

__device__ __forceinline__ void st_bf4_lds(__hip_bfloat16* p, const float* v) {
  union { __hip_bfloat16 b[4]; uint2 u; } t;
#pragma unroll
  for (int e = 0; e < 4; e++) t.b[e] = __float2bfloat16(v[e]);
  *(uint2*)p = t.u;
}

// ---------------------------------------------------------------------------
// prep_act: 8 rows/block, 512 threads (wave w owns row r0+w).
// Coalesced loads (lane l owns elems l*4 + q*256), shfl-only LN reduce,
// shfl conv carries, LDS-staged granule-order flush: per store instruction
// the wave writes 64 CONSECUTIVE granules (1KB contiguous) — fixes the
// 64B-chunk scatter of the 1-row version.
// Layouts byte-identical to prior rounds:
//  xh2 granule ((mb*4+n)*32 + ktl)*512 + rl*4 + pc : x ; +16 on ktl : h
//  xc2 granule ((mb*4+n)*16 + ktl)*512 + rl*4 + pc : SiLU(conv(LN(x)))
#define ROWP 2056  // LDS row pitch (bf16 elems): 4112B -> flush reads spread banks
__global__ __launch_bounds__(512, 2) void prep_act(
    const float* __restrict__ x, const float* __restrict__ h,
    const float* __restrict__ lg, const float* __restrict__ lb,
    const float* __restrict__ cw, const float* __restrict__ cb,
    __hip_bfloat16* __restrict__ xh2, __hip_bfloat16* __restrict__ xc2) {
  __shared__ __attribute__((aligned(16))) __hip_bfloat16 tile[8 * ROWP];  // 32.9KB
  const int t = threadIdx.x, w = t >> 6, l = t & 63;
  const int r0 = blockIdx.x * 8;
  const int mb = r0 >> 7, rl0 = r0 & 127;
  const int r = r0 + w;

  const float* xr = x + (size_t)r * 2048;
  const float* hr = h + (size_t)r * 2048;

  // ---- load x and h (coalesced: per instr, wave covers 1KB contiguous)
  float xv[32], hv[32];
#pragma unroll
  for (int q = 0; q < 8; q++) {
    float4 v = ((const float4*)xr)[l + q * 64];
    xv[q * 4 + 0] = v.x; xv[q * 4 + 1] = v.y; xv[q * 4 + 2] = v.z; xv[q * 4 + 3] = v.w;
  }
#pragma unroll
  for (int q = 0; q < 8; q++) {
    float4 v = ((const float4*)hr)[l + q * 64];
    hv[q * 4 + 0] = v.x; hv[q * 4 + 1] = v.y; hv[q * 4 + 2] = v.z; hv[q * 4 + 3] = v.w;
  }

  // ---- LN reduce (wave-wide shfl, no LDS, no barrier)
  float s = 0.f, s2 = 0.f;
#pragma unroll
  for (int e = 0; e < 32; e++) { s += xv[e]; s2 += xv[e] * xv[e]; }
#pragma unroll
  for (int off = 32; off > 0; off >>= 1) {
    s += __shfl_xor(s, off);
    s2 += __shfl_xor(s2, off);
  }
  const float mu = s * (1.0f / 2048.0f);
  const float var = s2 * (1.0f / 2048.0f) - mu * mu;
  const float rs = rsqrtf(var + 1e-5f);

  // ---- flush helper: part 0 = x, 1 = h, 2 = xc
#define FLUSH(PART)                                                            \
  do {                                                                         \
    _Pragma("unroll")                                                          \
    for (int k = 0; k < 4; ++k) {                                              \
      const int gi = k * 512 + t;                                              \
      const int pc = gi & 3, rr = (gi >> 2) & 7, grp = gi >> 5;                \
      const int n_ = grp >> 4, ktl_ = grp & 15;                                \
      const int c_ = pc ^ (((rl0 + rr) >> 1) & 3);                             \
      bf16x8 v = *(const bf16x8*)(tile + rr * ROWP + n_ * 512 + ktl_ * 32 + c_ * 8); \
      size_t G;                                                                \
      if ((PART) == 2)                                                         \
        G = ((size_t)(mb * 4 + n_) * 16 + ktl_) * 512 + (rl0 + rr) * 4 + pc;   \
      else                                                                     \
        G = ((size_t)(mb * 4 + n_) * 32 + ((PART) ? 16 : 0) + ktl_) * 512 +    \
            (rl0 + rr) * 4 + pc;                                               \
      *(bf16x8*)(((PART) == 2 ? xc2 : xh2) + G * 8) = v;                       \
    }                                                                          \
  } while (0)

  // ---- Round X
#pragma unroll
  for (int q = 0; q < 8; q++)
    st_bf4_lds(tile + w * ROWP + q * 256 + l * 4, &xv[q * 4]);
  __syncthreads();
  FLUSH(0);
  __syncthreads();

  // ---- Round H
#pragma unroll
  for (int q = 0; q < 8; q++)
    st_bf4_lds(tile + w * ROWP + q * 256 + l * 4, &hv[q * 4]);
  __syncthreads();
  FLUSH(1);
  __syncthreads();

  // ---- fr = LN(x)*g + b
  float fr[32];
#pragma unroll
  for (int q = 0; q < 8; q++) {
    float4 gv = ((const float4*)lg)[l + q * 64];
    float4 bv = ((const float4*)lb)[l + q * 64];
    fr[q * 4 + 0] = (xv[q * 4 + 0] - mu) * rs * gv.x + bv.x;
    fr[q * 4 + 1] = (xv[q * 4 + 1] - mu) * rs * gv.y + bv.y;
    fr[q * 4 + 2] = (xv[q * 4 + 2] - mu) * rs * gv.z + bv.z;
    fr[q * 4 + 3] = (xv[q * 4 + 3] - mu) * rs * gv.w + bv.w;
  }

  // ---- conv3 + SiLU, carries via shfl (lane l-1 same chunk; lane63 prev chunk)
  const float w0 = cw[0], w1 = cw[1], w2 = cw[2], cbv = cb[0];
  float c1 = 0.f, c2 = 0.f;  // prev-chunk lane63 fr[3], fr[2]
#pragma unroll
  for (int q = 0; q < 8; q++) {
    float pm1 = __shfl_up(fr[q * 4 + 3], 1);
    float pm2 = __shfl_up(fr[q * 4 + 2], 1);
    if (l == 0) { pm1 = c1; pm2 = c2; }
    float sc[4];
    {
      float v0 = w0 * pm2 + w1 * pm1 + w2 * fr[q * 4 + 0] + cbv;
      float v1 = w0 * pm1 + w1 * fr[q * 4 + 0] + w2 * fr[q * 4 + 1] + cbv;
      float v2 = w0 * fr[q * 4 + 0] + w1 * fr[q * 4 + 1] + w2 * fr[q * 4 + 2] + cbv;
      float v3 = w0 * fr[q * 4 + 1] + w1 * fr[q * 4 + 2] + w2 * fr[q * 4 + 3] + cbv;
      sc[0] = v0 * sigmoidf_(v0);
      sc[1] = v1 * sigmoidf_(v1);
      sc[2] = v2 * sigmoidf_(v2);
      sc[3] = v3 * sigmoidf_(v3);
    }
    c1 = __shfl(fr[q * 4 + 3], 63);
    c2 = __shfl(fr[q * 4 + 2], 63);
    st_bf4_lds(tile + w * ROWP + q * 256 + l * 4, sc);
  }
  __syncthreads();
  FLUSH(2);
}

// ---------------------------------------------------------------------------
// prep_wb: w-relayout (r4's coalesced LDS-transpose version) + bias.
//   blocks [0, 2048)     : w    (W/R f32 -> swizzled bf16 WT2)
//   blocks [2048, 2056)  : bias (b + rb)
__global__ __launch_bounds__(256) void prep_wb(
    const float* __restrict__ Wz, const float* __restrict__ Wi,
    const float* __restrict__ Wf, const float* __restrict__ Wo,
    const float* __restrict__ Rz, const float* __restrict__ Ri,
    const float* __restrict__ Rf, const float* __restrict__ Ro,
    __hip_bfloat16* __restrict__ WT2,
    const float* __restrict__ bz, const float* __restrict__ bi,
    const float* __restrict__ bf, const float* __restrict__ bo,
    const float* __restrict__ rbz, const float* __restrict__ rbi,
    const float* __restrict__ rbf, const float* __restrict__ rbo,
    float* __restrict__ bias) {
  __shared__ float smf[4224];  // [128][33] f32 transpose tile
  const int b = blockIdx.x, t = threadIdx.x;

  if (b < 2048) {
    const int jt = b & 15;          // 16 j-tiles of 32
    const int ksg = (b >> 4) & 7;   // 8 groups of 128 k
    const int gn = b >> 7;          // g*4 + n
    const int g = gn >> 2, nn = gn & 3;
    const float* src;
    if (ksg < 4) src = (g == 0 ? Wz : g == 1 ? Wi : g == 2 ? Wf : Wo);
    else         src = (g == 0 ? Rz : g == 1 ? Ri : g == 2 ? Rf : Ro);
    const int kb = (ksg & 3) * 128;

    {
      const int r8 = t >> 3, c4 = t & 7;
      const float* sp = src + ((size_t)nn * 512 + kb + r8) * 512 + jt * 32 + c4 * 4;
#pragma unroll
      for (int rr = 0; rr < 4; rr++) {
        float4 v = *(const float4*)(sp + (size_t)rr * 32 * 512);
        float* d = smf + (r8 + rr * 32) * 33 + c4 * 4;
        d[0] = v.x; d[1] = v.y; d[2] = v.z; d[3] = v.w;
      }
    }
    __syncthreads();
#pragma unroll
    for (int q = 0; q < 2; q++) {
      int u = t + q * 256;
      int ksl = u >> 7, j = (u >> 2) & 31, pc = u & 3;
      int c = pc ^ ((j >> 1) & 3);
      int krl = ksl * 32 + c * 8;
      float v[8];
#pragma unroll
      for (int e = 0; e < 8; e++) v[e] = smf[(krl + e) * 33 + j];
      size_t gr = ((size_t)(gn * 16 + jt) * 32 + ksg * 4 + ksl) * 128 + j * 4 + pc;
      store_bf8(WT2 + gr * 8, v);
    }

  } else {
    int i = (b - 2048) * 256 + t;
    if (i < 2048) {
      bias[0 * 2048 + i] = bz[i] + rbz[i];
      bias[1 * 2048 + i] = bi[i] + rbi[i];
      bias[2 * 2048 + i] = bf[i] + rbf[i];
      bias[3 * 2048 + i] = bo[i] + rbo[i];
    }
  }
}

// ---------------------------------------------------------------------------
// Fused 4-gate block GEMM + sLSTM epilogue (round-7 version, VERBATIM —
// best measured 123.5 us): fully-unrolled saddr-form dbuf, counted vmcnt.
__global__ __launch_bounds__(512, 4) void gemm_fused(
    const __hip_bfloat16* __restrict__ xh2, const __hip_bfloat16* __restrict__ xc2,
    const __hip_bfloat16* __restrict__ WT2, const float* __restrict__ bias,
    const float* __restrict__ c_prev, float* __restrict__ out) {
  __shared__ __attribute__((aligned(16))) char smem[65536];
  __hip_bfloat16* zo = (__hip_bfloat16*)smem;

  const int mb = blockIdx.x, jt = blockIdx.y, n = blockIdx.z;
  const int t = threadIdx.x, w = t >> 6, l = t & 63;
  const int pair = w >> 2, mhalf = (w >> 1) & 1, jhalf = w & 1;
  const int lj = l & 15;

  const char* gAu = (const char*)xh2 + (size_t)(mb * 4 + n) * 262144;
  const char* gCu = (const char*)xc2 + (size_t)(mb * 4 + n) * 131072;
  const char* gBu = (const char*)WT2 + (size_t)(n * 16 + jt * 2) * 65536;

  const int tA = t * 16;
  const int bg0 = t >> 8, bj0 = (t >> 7) & 1, br0 = t & 127;
  const int u1 = t + 512;
  const int bg1 = u1 >> 8, bj1 = (u1 >> 7) & 1, br1 = u1 & 127;
  const int vB0 = (bg0 * 64 + bj0) * 65536 + br0 * 16;
  const int vB1 = (bg1 * 64 + bj1) * 65536 + br1 * 16;
  const int dB0 = 16384 + bg0 * 4096 + bj0 * 2048 + br0 * 16;
  const int dB1 = 16384 + bg1 * 4096 + bj1 * 2048 + br1 * 16;

  const int fo = lj * 64 + (((l >> 4) ^ ((lj >> 1) & 3)) * 16);
  const int g0 = pair ? 1 : 0, g1 = pair ? 2 : 3;

  f32x4 acc[4][2][2] = {};

#define BAR() __builtin_amdgcn_s_barrier()
#define SBZ() __builtin_amdgcn_sched_barrier(0)

#define STAGE(H)                                                               \
  do {                                                                         \
    async16(gAu + ((H) * 8192 + 0) + tA, smem + ((H) & 1) * 32768 + tA);       \
    if ((H) < 16)                                                              \
      async16(gCu + ((H) * 8192) + tA, smem + ((H) & 1) * 32768 + 8192 + tA);  \
    async16(gBu + ((H) * 2048) + vB0, smem + ((H) & 1) * 32768 + dB0);         \
    async16(gBu + ((H) * 2048) + vB1, smem + ((H) & 1) * 32768 + dB1);         \
  } while (0)

#define MFMA8(sj, B0, B1)                                                      \
  do {                                                                         \
    acc[0][sj][0] = __builtin_amdgcn_mfma_f32_16x16x32_bf16(af0, B0, acc[0][sj][0], 0, 0, 0); \
    acc[1][sj][0] = __builtin_amdgcn_mfma_f32_16x16x32_bf16(af1, B0, acc[1][sj][0], 0, 0, 0); \
    acc[2][sj][0] = __builtin_amdgcn_mfma_f32_16x16x32_bf16(af2, B0, acc[2][sj][0], 0, 0, 0); \
    acc[3][sj][0] = __builtin_amdgcn_mfma_f32_16x16x32_bf16(af3, B0, acc[3][sj][0], 0, 0, 0); \
    acc[0][sj][1] = __builtin_amdgcn_mfma_f32_16x16x32_bf16(af0, B1, acc[0][sj][1], 0, 0, 0); \
    acc[1][sj][1] = __builtin_amdgcn_mfma_f32_16x16x32_bf16(af1, B1, acc[1][sj][1], 0, 0, 0); \
    acc[2][sj][1] = __builtin_amdgcn_mfma_f32_16x16x32_bf16(af2, B1, acc[2][sj][1], 0, 0, 0); \
    acc[3][sj][1] = __builtin_amdgcn_mfma_f32_16x16x32_bf16(af3, B1, acc[3][sj][1], 0, 0, 0); \
  } while (0)

#define STEP(KS)                                                               \
  do {                                                                         \
    if ((KS) < 31) STAGE((KS) + 1);                                            \
    wait_vmcnt<((KS) + 1 < 16) ? 4 : (((KS) + 1 < 32) ? 3 : 0)>();             \
    BAR(); SBZ();                                                              \
    const char* Ab = smem + ((KS) & 1) * 32768 +                               \
                     (((KS) < 16 && pair) ? 8192 : 0) + mhalf * 4096 + fo;     \
    const char* Bb = smem + ((KS) & 1) * 32768 + 16384 + jhalf * 2048 + fo;    \
    bf16x8 af0 = *(const bf16x8*)(Ab);                                         \
    bf16x8 af1 = *(const bf16x8*)(Ab + 1024);                                  \
    bf16x8 af2 = *(const bf16x8*)(Ab + 2048);                                  \
    bf16x8 af3 = *(const bf16x8*)(Ab + 3072);                                  \
    bf16x8 b00 = *(const bf16x8*)(Bb + g0 * 4096);                             \
    bf16x8 b10 = *(const bf16x8*)(Bb + g1 * 4096);                             \
    bf16x8 b01 = *(const bf16x8*)(Bb + g0 * 4096 + 1024);                      \
    bf16x8 b11 = *(const bf16x8*)(Bb + g1 * 4096 + 1024);                      \
    SBZ();                                                                     \
    __builtin_amdgcn_s_setprio(1);                                             \
    MFMA8(0, b00, b10);                                                        \
    MFMA8(1, b01, b11);                                                        \
    __builtin_amdgcn_s_setprio(0);                                             \
    SBZ(); BAR();                                                              \
  } while (0)

  STAGE(0);

  STEP(0);  STEP(1);  STEP(2);  STEP(3);
  STEP(4);  STEP(5);  STEP(6);  STEP(7);
  STEP(8);  STEP(9);  STEP(10); STEP(11);
  STEP(12); STEP(13); STEP(14); STEP(15);
  STEP(16); STEP(17); STEP(18); STEP(19);
  STEP(20); STEP(21); STEP(22); STEP(23);
  STEP(24); STEP(25); STEP(26); STEP(27);
  STEP(28); STEP(29); STEP(30); STEP(31);

  // ---- Epilogue. C/D 16x16: col = lane&15, row = (lane>>4)*4 + reg.
  const int r0 = (l >> 4) * 4;
  const int colb = n * 512 + jt * 64;
  __syncthreads();
  if (pair == 0) {
#pragma unroll
    for (int sj = 0; sj < 2; ++sj) {
      const int jc = jhalf * 32 + sj * 16 + lj;
      const float bz_ = bias[colb + jc];
      const float bo_ = bias[3 * 2048 + colb + jc];
#pragma unroll
      for (int s = 0; s < 4; ++s) {
#pragma unroll
        for (int rr = 0; rr < 4; ++rr) {
          const int rl = mhalf * 64 + s * 16 + r0 + rr;
          zo[rl * 72 + jc] = __float2bfloat16(tanhf_(acc[s][sj][0][rr] + bz_));
          zo[(128 + rl) * 72 + jc] = __float2bfloat16(sigmoidf_(acc[s][sj][1][rr] + bo_));
        }
      }
    }
  }
  __syncthreads();
  if (pair == 1) {
    const size_t HC = (size_t)BB * HH;
#pragma unroll
    for (int sj = 0; sj < 2; ++sj) {
      const int jc = jhalf * 32 + sj * 16 + lj;
      const int col = colb + jc;
      const float bi_ = bias[1 * 2048 + col];
      const float bf_ = bias[2 * 2048 + col];
#pragma unroll
      for (int s = 0; s < 4; ++s) {
#pragma unroll
        for (int rr = 0; rr < 4; ++rr) {
          const int rl = mhalf * 64 + s * 16 + r0 + rr;
          const int row = mb * 128 + rl;
          const float z  = __bfloat162float(zo[rl * 72 + jc]);
          const float og = __bfloat162float(zo[(128 + rl) * 72 + jc]);
          const float ig = sigmoidf_(acc[s][sj][0][rr] + bi_);
          const float fg = sigmoidf_(acc[s][sj][1][rr] + bf_);
          const float cp = c_prev[(size_t)row * 2048 + col];
          const float c = fg * cp + ig * z;
          const float hv = og * tanhf_(c);
          out[(size_t)row * 2048 + col] = hv;
          out[HC + (size_t)row * 2048 + col] = c;
        }
      }
    }
  }
}

// ---------------------------------------------------------------------------
extern "C" void kernel_launch(void* const* d_in, const int* in_sizes, int n_in,
                              void* d_out, int out_size, void* d_ws, size_t ws_size,
                              hipStream_t stream) {
  const float* x      = (const float*)d_in[0];
  const float* h_prev = (const float*)d_in[1];
  const float* c_prev = (const float*)d_in[2];
  const float* ln_g   = (const float*)d_in[3];
  const float* ln_b   = (const float*)d_in[4];
  const float* conv_w = (const float*)d_in[5];
  const float* conv_b = (const float*)d_in[6];
  const float* Wz = (const float*)d_in[7];
  const float* bz = (const float*)d_in[8];
  const float* Wi = (const float*)d_in[9];
  const float* bi = (const float*)d_in[10];
  const float* Wf = (const float*)d_in[11];
  const float* bf = (const float*)d_in[12];
  const float* Wo = (const float*)d_in[13];
  const float* bo = (const float*)d_in[14];
  const float* Rz = (const float*)d_in[15];
  const float* rbz = (const float*)d_in[16];
  const float* Ri = (const float*)d_in[17];
  const float* rbi = (const float*)d_in[18];
  const float* Rf = (const float*)d_in[19];
  const float* rbf = (const float*)d_in[20];
  const float* Ro = (const float*)d_in[21];
  const float* rbo = (const float*)d_in[22];
  float* out = (float*)d_out;

  char* ws = (char*)d_ws;
  __hip_bfloat16* xh2 = (__hip_bfloat16*)(ws);                       // 32 MiB
  __hip_bfloat16* xc2 = (__hip_bfloat16*)(ws + 33554432);            // 16 MiB
  __hip_bfloat16* WT2 = (__hip_bfloat16*)(ws + 33554432 + 16777216); // 16 MiB
  float* bias         = (float*)(ws + 33554432 + 2 * 16777216);      // 32 KiB

  prep_wb<<<2056, 256, 0, stream>>>(
      Wz, Wi, Wf, Wo, Rz, Ri, Rf, Ro, WT2,
      bz, bi, bf, bo, rbz, rbi, rbf, rbo, bias);
  prep_act<<<512, 512, 0, stream>>>(
      x, h_prev, ln_g, ln_b, conv_w, conv_b, xh2, xc2);
  gemm_fused<<<dim3(32, 8, 4), 512, 0, stream>>>(xh2, xc2, WT2, bias, c_prev, out);
}